// Round 13
// baseline (123.917 us; speedup 1.0000x reference)
//
#include <hip/hip_runtime.h>
#include <hip/hip_bf16.h>

#define ALPHA 100.0f
#define CUT   0.0625f   // d^2 cutoff: exp(-100*CUT)=1.9e-3 << 2e-2 threshold
// 8x8x8 cells of size 0.125; cull tris whose AABB-gap^2 to the cell box > CUT.

// ---------------- workspace layout (bytes) ----------------
// pre:    0            .. 384K        4096 tris * 6 float4
// pcount: 384K         .. +8K         2048 int
// plist:  392K         .. +1M         2048*256 u16
// tcount: 392K+1M      .. +8K         2048 int
// tlist:  400K+1M      .. +4M         2048*1024 u16
#define OFF_PCOUNT (384*1024)
#define OFF_PLIST  (OFF_PCOUNT + 2048*4)
#define OFF_TCOUNT (OFF_PLIST + 2048*256*2)
#define OFF_TLIST  (OFF_TCOUNT + 2048*4)

__global__ __launch_bounds__(1024) void zero_counts(int* pcount) {
    int i = blockIdx.x * 1024 + threadIdx.x;
    if (i < 2048) pcount[i] = 0;
}

// Per-triangle invariants: q0: v0.xyz, dt(=denom or -1)   q1: e0.xyz, dot00
// q2: e1.xyz, dot11   q3: nn.xyz, dot01   q4: inv00, inv11, c12, invab   q5: abab
__global__ __launch_bounds__(256) void rast_pre(const float* __restrict__ tv,
                                                float4* __restrict__ pre) {
    int i = blockIdx.x * 256 + threadIdx.x;   // 0..4095
    if (i >= 4096) return;
    const float* t = tv + (size_t)i * 9;
    float v0x = t[0], v0y = t[1], v0z = t[2];
    float v1x = t[3], v1y = t[4], v1z = t[5];
    float v2x = t[6], v2y = t[7], v2z = t[8];

    float e0x = v1x - v0x, e0y = v1y - v0y, e0z = v1z - v0z;
    float e1x = v2x - v0x, e1y = v2y - v0y, e1z = v2z - v0z;

    float nx = e0y * e1z - e0z * e1y;
    float ny = e0z * e1x - e0x * e1z;
    float nz = e0x * e1y - e0y * e1x;
    float area2 = nx * nx + ny * ny + nz * nz;

    float dot00 = e0x * e0x + e0y * e0y + e0z * e0z;
    float dot01 = e0x * e1x + e0y * e1y + e0z * e1z;
    float dot11 = e1x * e1x + e1y * e1y + e1z * e1z;

    float denom = fmaxf(area2, 1e-12f);
    double rs   = 1.0 / sqrt((double)denom);
    float nnx = (float)(nx * rs), nny = (float)(ny * rs), nnz = (float)(nz * rs);

    float inv00 = 1.0f / fmaxf(dot00, 1e-12f);
    float inv11 = 1.0f / fmaxf(dot11, 1e-12f);
    float abab  = dot00 - 2.0f * dot01 + dot11;
    float invab = 1.0f / fmaxf(abab, 1e-12f);
    float dt    = (area2 >= 4e-10f) ? denom : -1.0f;
    float c12   = dot00 - dot01;

    float4* q = pre + (size_t)i * 6;
    q[0] = make_float4(v0x, v0y, v0z, dt);
    q[1] = make_float4(e0x, e0y, e0z, dot00);
    q[2] = make_float4(e1x, e1y, e1z, dot11);
    q[3] = make_float4(nnx, nny, nnz, dot01);
    q[4] = make_float4(inv00, inv11, c12, invab);
    q[5] = make_float4(abab, 0.0f, 0.0f, 0.0f);
}

// Bin 32768 points into (batch, cell) lists. Order within a list is
// nondeterministic (atomics) but the final min/output is order-invariant.
__global__ __launch_bounds__(1024) void point_bin(const float* __restrict__ pts,
                                                  int* __restrict__ pcount,
                                                  unsigned short* __restrict__ plist) {
    int i = blockIdx.x * 1024 + threadIdx.x;   // 0..32767
    int batch = i >> 13;
    const float* p = pts + (size_t)i * 3;
    float x = p[0], y = p[1], z = p[2];
    int cx = min(7, max(0, (int)(x * 8.0f)));
    int cy = min(7, max(0, (int)(y * 8.0f)));
    int cz = min(7, max(0, (int)(z * 8.0f)));
    int bc = batch * 512 + (cz * 64 + cy * 8 + cx);
    int slot = atomicAdd(&pcount[bc], 1);
    if (slot < 256) plist[bc * 256 + slot] = (unsigned short)(i & 8191);
}

// Per (batch,cell) block: keep triangles whose AABB-to-cellbox gap^2 <= CUT.
__global__ __launch_bounds__(256) void tri_bin(const float* __restrict__ tv,
                                               int* __restrict__ tcount,
                                               unsigned short* __restrict__ tlist) {
    int bc = blockIdx.x;                 // 0..2047
    int batch = bc >> 9, cell = bc & 511;
    int cx = cell & 7, cy = (cell >> 3) & 7, cz = cell >> 6;
    float lx = cx * 0.125f, hx = lx + 0.125f;
    float ly = cy * 0.125f, hy = ly + 0.125f;
    float lz = cz * 0.125f, hz = lz + 0.125f;

    __shared__ int tc;
    if (threadIdx.x == 0) tc = 0;
    __syncthreads();

#pragma unroll
    for (int k = 0; k < 4; ++k) {
        int ti = k * 256 + threadIdx.x;  // 0..1023
        const float* t = tv + ((size_t)batch * 1024 + ti) * 9;
        float x0 = t[0], y0 = t[1], z0 = t[2];
        float x1 = t[3], y1 = t[4], z1 = t[5];
        float x2 = t[6], y2 = t[7], z2 = t[8];
        float mnx = fminf(fminf(x0, x1), x2), mxx = fmaxf(fmaxf(x0, x1), x2);
        float mny = fminf(fminf(y0, y1), y2), mxy = fmaxf(fmaxf(y0, y1), y2);
        float mnz = fminf(fminf(z0, z1), z2), mxz = fmaxf(fmaxf(z0, z1), z2);
        float gx = fmaxf(0.0f, fmaxf(lx - mxx, mnx - hx));
        float gy = fmaxf(0.0f, fmaxf(ly - mxy, mny - hy));
        float gz = fmaxf(0.0f, fmaxf(lz - mxz, mnz - hz));
        float g2 = gx * gx + gy * gy + gz * gz;
        if (g2 <= CUT) {
            int slot = atomicAdd(&tc, 1);
            tlist[bc * 1024 + slot] = (unsigned short)ti;
        }
    }
    __syncthreads();
    if (threadIdx.x == 0) tcount[bc] = tc;
}

// point vs one triangle -> dist^2 (same verified math as prior rounds)
__device__ __forceinline__ float tri_d2(float px, float py, float pz,
                                        const float4& q0, const float4& q1,
                                        const float4& q2, const float4& q3,
                                        const float4& q4, const float4& q5) {
    float dx = px - q0.x, dy = py - q0.y, dz = pz - q0.z;
    float dd = dx * dx + dy * dy + dz * dz;
    float a0 = q1.x * dx + q1.y * dy + q1.z * dz;
    float a1 = q2.x * dx + q2.y * dy + q2.z * dz;
    float dn = q3.x * dx + q3.y * dy + q3.z * dz;

    float U = q2.w * a0 - q3.w * a1;
    float V = q1.w * a1 - q3.w * a0;
    float W = q0.w - (U + V);
    float plane = dn * dn;

    float a02 = a0 + a0;
    float t1 = fminf(fmaxf(a0 * q4.x, 0.f), 1.f);
    float s1 = dd + t1 * (t1 * q1.w - a02);
    float a12 = a1 + a1;
    float t2 = fminf(fmaxf(a1 * q4.y, 0.f), 1.f);
    float s2 = dd + t2 * (t2 * q2.w - a12);
    float pab  = (q4.z + a1) - a0;
    float papa = (dd - a02) + q1.w;
    float t3 = fminf(fmaxf(pab * q4.w, 0.f), 1.f);
    float s3 = papa + t3 * (t3 * q5.x - (pab + pab));

    float edge = fminf(fminf(s1, s2), s3);
    float ins  = fminf(fminf(U, V), W);
    return (ins >= 0.0f) ? plane : edge;
}

// Block per (batch, cell): lane = triangle slot in the cell's culled list,
// LDS-broadcast points, stride-17 LDS accumulate + 2-stage reduce.
// Culled floor: min initialized to CUT -> output exp(-100*CUT)=1.9e-3 (safe).
__global__ __launch_bounds__(256) void rast_cell(const float* __restrict__ pts,
                                                 const float4* __restrict__ pre,
                                                 const int* __restrict__ pcount,
                                                 const unsigned short* __restrict__ plist,
                                                 const int* __restrict__ tcount,
                                                 const unsigned short* __restrict__ tlist,
                                                 float* __restrict__ out) {
    int bc = blockIdx.x;
    int batch = bc >> 9;
    int t = threadIdx.x;
    int nP = min(pcount[bc], 256);
    int nT = tcount[bc];
    if (nP == 0) return;

    __shared__ float4 spt[256];
    __shared__ int    spid[256];
    __shared__ float  red[256 * 17];
    __shared__ float  part[256];

    if (t < nP) {
        int pi = plist[bc * 256 + t];
        const float* pp = pts + ((size_t)batch * 8192 + pi) * 3;
        spt[t]  = make_float4(pp[0], pp[1], pp[2], 0.0f);
        spid[t] = pi;
    }
    __syncthreads();

    int nchunk = (nT + 255) >> 8;
    for (int p0 = 0; p0 < nP; p0 += 16) {
        int cnt = min(16, nP - p0);
#pragma unroll
        for (int j = 0; j < 16; ++j) red[t * 17 + j] = CUT;  // own slots, prior pass synced
        for (int c = 0; c < nchunk; ++c) {
            int ti = c * 256 + t;
            if (ti < nT) {
                int tid2 = tlist[bc * 1024 + ti];
                const float4* q = pre + ((size_t)batch * 1024 + tid2) * 6;
                float4 q0 = q[0], q1 = q[1], q2 = q[2], q3 = q[3], q4 = q[4], q5 = q[5];
#pragma unroll
                for (int j = 0; j < 16; ++j) {
                    float4 p = spt[p0 + j];          // uniform address -> broadcast
                    float m = tri_d2(p.x, p.y, p.z, q0, q1, q2, q3, q4, q5);
                    red[t * 17 + j] = fminf(red[t * 17 + j], m);
                }
            }
        }
        __syncthreads();
        int pj = t & 15, g = t >> 4;
        float m = 3.4e38f;
#pragma unroll
        for (int s = 0; s < 16; ++s) m = fminf(m, red[(g * 16 + s) * 17 + pj]);
        part[t] = m;
        __syncthreads();
        if (t < cnt) {
            float mm = part[t];
#pragma unroll
            for (int g2 = 1; g2 < 16; ++g2) mm = fminf(mm, part[g2 * 16 + t]);
            out[(size_t)batch * 8192 + spid[p0 + t]] = __expf(-ALPHA * mm);
        }
        __syncthreads();
    }
}

extern "C" void kernel_launch(void* const* d_in, const int* in_sizes, int n_in,
                              void* d_out, int out_size, void* d_ws, size_t ws_size,
                              hipStream_t stream) {
    const float* pts = (const float*)d_in[0];   // (4, 8192, 3)
    const float* tv  = (const float*)d_in[1];   // (4, 1024, 3, 3)
    float* out = (float*)d_out;                 // (4, 8192)

    char* ws = (char*)d_ws;
    float4*         pre    = (float4*)ws;
    int*            pcount = (int*)(ws + OFF_PCOUNT);
    unsigned short* plist  = (unsigned short*)(ws + OFF_PLIST);
    int*            tcount = (int*)(ws + OFF_TCOUNT);
    unsigned short* tlist  = (unsigned short*)(ws + OFF_TLIST);

    zero_counts<<<2, 1024, 0, stream>>>(pcount);
    rast_pre<<<16, 256, 0, stream>>>(tv, pre);
    point_bin<<<32, 1024, 0, stream>>>(pts, pcount, plist);
    tri_bin<<<2048, 256, 0, stream>>>(tv, tcount, tlist);
    rast_cell<<<2048, 256, 0, stream>>>(pts, pre, pcount, plist, tcount, tlist, out);
}

// Round 14
// 87.561 us; speedup vs baseline: 1.4152x; 1.4152x over previous
//
#include <hip/hip_runtime.h>
#include <hip/hip_bf16.h>

#define ALPHA 100.0f

typedef float v2f __attribute__((ext_vector_type(2)));

// ---- forced VOP3P packed-f32 (gfx90a+/gfx950): 2 lanes of math per instr ----
__device__ __forceinline__ v2f pk_add(v2f a, v2f b) {
    v2f d; asm("v_pk_add_f32 %0, %1, %2" : "=v"(d) : "v"(a), "v"(b)); return d;
}
__device__ __forceinline__ v2f pk_sub(v2f a, v2f b) {   // a - b
    v2f d; asm("v_pk_add_f32 %0, %1, %2 neg_lo:[0,1] neg_hi:[0,1]" : "=v"(d) : "v"(a), "v"(b)); return d;
}
__device__ __forceinline__ v2f pk_mul(v2f a, v2f b) {
    v2f d; asm("v_pk_mul_f32 %0, %1, %2" : "=v"(d) : "v"(a), "v"(b)); return d;
}
__device__ __forceinline__ v2f pk_fma(v2f a, v2f b, v2f c) {  // a*b + c
    v2f d; asm("v_pk_fma_f32 %0, %1, %2, %3" : "=v"(d) : "v"(a), "v"(b), "v"(c)); return d;
}
__device__ __forceinline__ v2f pk_fms(v2f a, v2f b, v2f c) {  // a*b - c
    v2f d; asm("v_pk_fma_f32 %0, %1, %2, %3 neg_lo:[0,0,1] neg_hi:[0,0,1]" : "=v"(d) : "v"(a), "v"(b), "v"(c)); return d;
}
__device__ __forceinline__ v2f pk_nfma(v2f a, v2f b, v2f c) { // -a*b + c
    v2f d; asm("v_pk_fma_f32 %0, %1, %2, %3 neg_lo:[1,0,0] neg_hi:[1,0,0]" : "=v"(d) : "v"(a), "v"(b), "v"(c)); return d;
}

// Per-triangle precomputed invariants: 6 x float4 = 96 B
//  q0: v0.xyz, dt(=denom or -1)  q1: e0.xyz, dot00   q2: e1.xyz, dot11
//  q3: nn.xyz, dot01 (nn = n * rsqrt(denom))
//  q4: inv00, inv11, c12, invab   q5: abab, -, -, -
__global__ __launch_bounds__(256) void rast_pre(const float* __restrict__ tv,
                                                float4* __restrict__ pre) {
    int i = blockIdx.x * 256 + threadIdx.x;   // 0..4095
    if (i >= 4096) return;
    const float* t = tv + (size_t)i * 9;
    float v0x = t[0], v0y = t[1], v0z = t[2];
    float v1x = t[3], v1y = t[4], v1z = t[5];
    float v2x = t[6], v2y = t[7], v2z = t[8];

    float e0x = v1x - v0x, e0y = v1y - v0y, e0z = v1z - v0z;
    float e1x = v2x - v0x, e1y = v2y - v0y, e1z = v2z - v0z;

    float nx = e0y * e1z - e0z * e1y;
    float ny = e0z * e1x - e0x * e1z;
    float nz = e0x * e1y - e0y * e1x;
    float area2 = nx * nx + ny * ny + nz * nz;

    float dot00 = e0x * e0x + e0y * e0y + e0z * e0z;
    float dot01 = e0x * e1x + e0y * e1y + e0z * e1z;
    float dot11 = e1x * e1x + e1y * e1y + e1z * e1z;

    float denom = fmaxf(area2, 1e-12f);
    double rs   = 1.0 / sqrt((double)denom);
    float nnx = (float)(nx * rs), nny = (float)(ny * rs), nnz = (float)(nz * rs);

    float inv00 = 1.0f / fmaxf(dot00, 1e-12f);
    float inv11 = 1.0f / fmaxf(dot11, 1e-12f);
    float abab  = dot00 - 2.0f * dot01 + dot11;
    float invab = 1.0f / fmaxf(abab, 1e-12f);
    float dt    = (area2 >= 4e-10f) ? denom : -1.0f;
    float c12   = dot00 - dot01;

    float4* q = pre + (size_t)i * 6;
    q[0] = make_float4(v0x, v0y, v0z, dt);
    q[1] = make_float4(e0x, e0y, e0z, dot00);
    q[2] = make_float4(e1x, e1y, e1z, dot11);
    q[3] = make_float4(nnx, nny, nnz, dot01);
    q[4] = make_float4(inv00, inv11, c12, invab);
    q[5] = make_float4(abab, 0.0f, 0.0f, 0.0f);
}

// Two triangles packed as float2 halves.
struct TP {
    v2f v0x, v0y, v0z, dt;
    v2f e0x, e0y, e0z, d00;
    v2f e1x, e1y, e1z, d11;
    v2f nnx, nny, nnz, d01;
    v2f i00, i11, c12, iab;
    v2f ab;
};

__device__ __forceinline__ void load_pair(const float4* __restrict__ p6,
                                          int ta, int tb, TP& t) {
    const float4* qa = p6 + (size_t)ta * 6;
    const float4* qb = p6 + (size_t)tb * 6;
    float4 a0 = qa[0], a1 = qa[1], a2 = qa[2], a3 = qa[3], a4 = qa[4], a5 = qa[5];
    float4 b0 = qb[0], b1 = qb[1], b2 = qb[2], b3 = qb[3], b4 = qb[4], b5 = qb[5];
    t.v0x = (v2f){a0.x, b0.x}; t.v0y = (v2f){a0.y, b0.y}; t.v0z = (v2f){a0.z, b0.z}; t.dt  = (v2f){a0.w, b0.w};
    t.e0x = (v2f){a1.x, b1.x}; t.e0y = (v2f){a1.y, b1.y}; t.e0z = (v2f){a1.z, b1.z}; t.d00 = (v2f){a1.w, b1.w};
    t.e1x = (v2f){a2.x, b2.x}; t.e1y = (v2f){a2.y, b2.y}; t.e1z = (v2f){a2.z, b2.z}; t.d11 = (v2f){a2.w, b2.w};
    t.nnx = (v2f){a3.x, b3.x}; t.nny = (v2f){a3.y, b3.y}; t.nnz = (v2f){a3.z, b3.z}; t.d01 = (v2f){a3.w, b3.w};
    t.i00 = (v2f){a4.x, b4.x}; t.i11 = (v2f){a4.y, b4.y}; t.c12 = (v2f){a4.z, b4.z}; t.iab = (v2f){a4.w, b4.w};
    t.ab  = (v2f){a5.x, b5.x};
}

// point (pre-duplicated v2f halves) vs 2 packed triangles; returns updated min.
// All mul/add/fma chains forced to VOP3P packed-f32; clamps/min3/select scalar.
__device__ __forceinline__ float pair_min(v2f ppx, v2f ppy, v2f ppz,
                                          const TP& g, float prev) {
    v2f dx = pk_sub(ppx, g.v0x), dy = pk_sub(ppy, g.v0y), dz = pk_sub(ppz, g.v0z);
    v2f dd = pk_mul(dx, dx); dd = pk_fma(dy, dy, dd); dd = pk_fma(dz, dz, dd);
    v2f a0 = pk_mul(g.e0x, dx); a0 = pk_fma(g.e0y, dy, a0); a0 = pk_fma(g.e0z, dz, a0);
    v2f a1 = pk_mul(g.e1x, dx); a1 = pk_fma(g.e1y, dy, a1); a1 = pk_fma(g.e1z, dz, a1);
    v2f dn = pk_mul(g.nnx, dx); dn = pk_fma(g.nny, dy, dn); dn = pk_fma(g.nnz, dz, dn);

    v2f U = pk_nfma(g.d01, a1, pk_mul(g.d11, a0));   // d11*a0 - d01*a1
    v2f V = pk_nfma(g.d01, a0, pk_mul(g.d00, a1));   // d00*a1 - d01*a0
    v2f W = pk_sub(g.dt, pk_add(U, V));
    v2f plane = pk_mul(dn, dn);

    v2f a02 = pk_add(a0, a0);
    v2f m1  = pk_mul(a0, g.i00);
    v2f t1; t1.x = fminf(fmaxf(m1.x, 0.f), 1.f); t1.y = fminf(fmaxf(m1.y, 0.f), 1.f);  // v_med3
    v2f s1 = pk_fma(t1, pk_fms(t1, g.d00, a02), dd);

    v2f a12 = pk_add(a1, a1);
    v2f m2  = pk_mul(a1, g.i11);
    v2f t2; t2.x = fminf(fmaxf(m2.x, 0.f), 1.f); t2.y = fminf(fmaxf(m2.y, 0.f), 1.f);
    v2f s2 = pk_fma(t2, pk_fms(t2, g.d11, a12), dd);

    v2f pab  = pk_sub(pk_add(g.c12, a1), a0);
    v2f papa = pk_add(pk_sub(dd, a02), g.d00);
    v2f m3   = pk_mul(pab, g.iab);
    v2f t3; t3.x = fminf(fmaxf(m3.x, 0.f), 1.f); t3.y = fminf(fmaxf(m3.y, 0.f), 1.f);
    v2f pab2 = pk_add(pab, pab);
    v2f s3 = pk_fma(t3, pk_fms(t3, g.ab, pab2), papa);

    float ex = fminf(fminf(s1.x, s2.x), s3.x);           // v_min3
    float ey = fminf(fminf(s1.y, s2.y), s3.y);
    float ix = fminf(fminf(U.x, V.x), W.x);              // v_min3
    float iy = fminf(fminf(U.y, V.y), W.y);
    float rx = (ix >= 0.f) ? plane.x : ex;
    float ry = (iy >= 0.f) ? plane.y : ey;
    return fminf(fminf(rx, ry), prev);                   // v_min3
}

// Grid: 2048 blocks x 256 threads (4 waves), launch_bounds(256,4) -> VGPR<=128.
// block -> (batch = blk>>9, point-group = blk&511 -> 16 points).
// Lane holds 4 triangles as two packed TPs in registers; per point j: uniform
// ds_read broadcast of the point, packed-VOP3P body, ds_write of the lane min
// into a stride-17 (conflict-free) reduction tile; 2-stage LDS reduce.
__global__ __launch_bounds__(256, 4) void rast_main(const float* __restrict__ pts,
                                                    const float4* __restrict__ pre,
                                                    float* __restrict__ out) {
    int blk  = blockIdx.x;
    int b    = blk >> 9;          // batch
    int pg   = blk & 511;         // point group of 16
    int base = (b << 13) + (pg << 4);
    int t    = threadIdx.x;
    int lane = t & 63;
    int wave = __builtin_amdgcn_readfirstlane(t >> 6);   // 0..3

    const float4* p6 = pre + (size_t)b * 1024 * 6;
    int ta = wave * 128 + lane;

    TP g0, g1;
    load_pair(p6, ta,       ta + 64,  g0);
    load_pair(p6, ta + 512, ta + 576, g1);

    __shared__ float4 sp4[16];           // points of this group
    __shared__ float  red[256 * 17];     // padded stride 17 -> conflict-free
    __shared__ float  part[256];

    if (t < 16) {
        const float* pp = pts + (size_t)(base + t) * 3;
        sp4[t] = make_float4(pp[0], pp[1], pp[2], 0.0f);
    }
    __syncthreads();

    int ra = t * 17;
#pragma unroll 2
    for (int j = 0; j < 16; ++j) {
        float4 p = sp4[j];               // uniform address -> LDS broadcast
        v2f ppx = (v2f){p.x, p.x};
        v2f ppy = (v2f){p.y, p.y};
        v2f ppz = (v2f){p.z, p.z};
        float m = pair_min(ppx, ppy, ppz, g0, 3.4e38f);
        m       = pair_min(ppx, ppy, ppz, g1, m);
        red[ra + j] = m;
    }
    __syncthreads();

    // --- block reduce: min over 256 threads for each of 16 points ---
    int p = t & 15, g = t >> 4;          // 16 groups x 16 source-threads
    float m = 3.4e38f;
#pragma unroll
    for (int s = 0; s < 16; ++s) m = fminf(m, red[(g * 16 + s) * 17 + p]);
    part[t] = m;
    __syncthreads();
    if (t < 16) {
        float mm = part[t];
#pragma unroll
        for (int g2 = 1; g2 < 16; ++g2) mm = fminf(mm, part[g2 * 16 + t]);
        out[base + t] = __expf(-ALPHA * mm);
    }
}

extern "C" void kernel_launch(void* const* d_in, const int* in_sizes, int n_in,
                              void* d_out, int out_size, void* d_ws, size_t ws_size,
                              hipStream_t stream) {
    const float* pts = (const float*)d_in[0];   // (4, 8192, 3)
    const float* tv  = (const float*)d_in[1];   // (4, 1024, 3, 3)
    float* out = (float*)d_out;                 // (4, 8192)
    float4* pre = (float4*)d_ws;                // 4096 * 6 float4 = 384 KB

    rast_pre<<<16, 256, 0, stream>>>(tv, pre);
    rast_main<<<2048, 256, 0, stream>>>(pts, pre, out);
}